// Round 7
// baseline (86.538 us; speedup 1.0000x reference)
//
#include <hip/hip_runtime.h>
#include <hip/hip_fp8.h>
#include <stdint.h>
#include <stddef.h>

#define BATCH 8192
#define DIM   256

#define LN2F 0.6931471805599453f
// operand quantization scales; product = 1000*log2(e) = 1442.6950408889634
// so MFMA accs are directly exp2-domain scores (no dequant in hot loop).
#define SCALE_ZJ 16.0f                 // A side (staged)
#define SCALE_ZI 90.16844005556021f    // B side (regs)

typedef int   v8i    __attribute__((ext_vector_type(8)));   // 32B fp8 frag (8 VGPR)
typedef float f32x16 __attribute__((ext_vector_type(16)));  // 32x32 MFMA acc

// Fragment-slot-tiled layout for Zi8/Zj8 (tile = 32 rows x 256B = 8KB):
//   elem(row, kb) -> tile(row>>5)*8192 + q*2048 + c*1024 + (32h + (row&31))*16 + b
//   where kb = q*64 + h*32 + c*16 + b  (q<4, h<2, c<2, b<16).
// Slot index (32h + r32) == MFMA lane id, so:
//   - A-frag ds_read: one vaddr (lane*16) + imm offsets, conflict-free
//   - staging: identity mapping, linear & fully coalesced
//   - B-frag global loads: lane*16 contiguous, fully coalesced.

// ---------- helpers ----------
static __device__ __forceinline__ uint8_t f2fp8(float f) {
  __hip_fp8_e4m3 q(f);                       // OCP e4m3fn, RNE+sat
  return *reinterpret_cast<uint8_t*>(&q);
}

// stage one 8KB tile: identity mapping (LDS offset == source offset)
static __device__ __forceinline__ void stage8(const uint8_t* __restrict__ src,
                                              uint8_t* dst, int tid) {
#pragma unroll
  for (int it = 0; it < 2; ++it) {
    const int off = it * 4096 + tid * 16;
    __builtin_amdgcn_global_load_lds(
        (const __attribute__((address_space(1))) void*)(src + off),
        (__attribute__((address_space(3))) void*)(dst + off),
        16, 0, 0);
  }
}

// ---------- pass 1: normalize, exact fp32 positives, tiled fp8 store -------
__global__ __launch_bounds__(256) void prep_kernel(
    const float* __restrict__ p1, const float* __restrict__ p2,
    uint8_t* __restrict__ Zi8, uint8_t* __restrict__ Zj8,
    float* __restrict__ pos) {
  const int lane = threadIdx.x & 63;
  const int w    = threadIdx.x >> 6;
  const int row  = blockIdx.x * 4 + w;   // one wave per row

  const float4 x1 = ((const float4*)p1)[row * 64 + lane];
  const float4 x2 = ((const float4*)p2)[row * 64 + lane];
  float ss1 = x1.x * x1.x + x1.y * x1.y + x1.z * x1.z + x1.w * x1.w;
  float ss2 = x2.x * x2.x + x2.y * x2.y + x2.z * x2.z + x2.w * x2.w;
  float d   = x1.x * x2.x + x1.y * x2.y + x1.z * x2.z + x1.w * x2.w;
#pragma unroll
  for (int m = 1; m < 64; m <<= 1) {
    ss1 += __shfl_xor(ss1, m);
    ss2 += __shfl_xor(ss2, m);
    d   += __shfl_xor(d, m);
  }
  const float n1 = fmaxf(sqrtf(ss1), 1e-12f);
  const float n2 = fmaxf(sqrtf(ss2), 1e-12f);
  if (lane == 0) pos[row] = d / (n1 * n2);          // exact fp32 diagonal

  const float sI = SCALE_ZI / n1;
  const float sJ = SCALE_ZJ / n2;
  uchar4 u1, u2;
  u1.x = f2fp8(x1.x * sI); u1.y = f2fp8(x1.y * sI);
  u1.z = f2fp8(x1.z * sI); u1.w = f2fp8(x1.w * sI);
  u2.x = f2fp8(x2.x * sJ); u2.y = f2fp8(x2.y * sJ);
  u2.z = f2fp8(x2.z * sJ); u2.w = f2fp8(x2.w * sJ);

  // lane holds kb = 4*lane .. 4*lane+3 -> tiled address
  const size_t tb = (size_t)(row >> 5) * 8192;
  const int off = (lane >> 4) * 2048 + ((lane >> 2) & 1) * 1024 +
                  (((lane >> 3) & 1) * 32 + (row & 31)) * 16 + (lane & 3) * 4;
  *(uchar4*)(Zi8 + tb + off) = u1;
  *(uchar4*)(Zj8 + tb + off) = u2;
}

// ---------- online lse update for one 16-score acc block (lean temps) ------
static __device__ __forceinline__ void lse_update(const f32x16& acc,
                                                  float& m, float& l) {
  float t0 = fmaxf(fmaxf(acc[0],  acc[1]),  acc[2]);
  float t1 = fmaxf(fmaxf(acc[3],  acc[4]),  acc[5]);
  float t2 = fmaxf(fmaxf(acc[6],  acc[7]),  acc[8]);
  float t3 = fmaxf(fmaxf(acc[9],  acc[10]), acc[11]);
  t0 = fmaxf(fmaxf(t0, t1), fmaxf(fmaxf(acc[12], acc[13]), acc[14]));
  t2 = fmaxf(fmaxf(t2, t3), acc[15]);
  const float mn = fmaxf(m, fmaxf(t0, t2));
  float s0 = 0.f, s1 = 0.f;
#pragma unroll
  for (int r = 0; r < 16; r += 2) {
    s0 += __builtin_amdgcn_exp2f(acc[r + 0] - mn);
    s1 += __builtin_amdgcn_exp2f(acc[r + 1] - mn);
  }
  l = l * __builtin_amdgcn_exp2f(m - mn) + (s0 + s1);
  m = mn;
}

// ---------- pass 2: fused fp8 MFMA GEMM + online logsumexp ----------
// acc = mfma_scale_32x32x64(A=Zj_frag, B=Zi_frag, unit scales) -> D[j][i],
// col(lane&31)=i. Each lane owns TWO i rows; scalar (m,l) per row.
// grid = 32 row-blocks (256 i) x 32 j-chunks (256 cols); chunk = bid&31 so
// same-chunk blocks share an XCD (bid%8 == chunk%8), Zj slice L2-local.
__global__ __launch_bounds__(256, 4) void lse_kernel(
    const uint8_t* __restrict__ Zi8, const uint8_t* __restrict__ Zj8,
    float* __restrict__ plse) {
  const int bid   = blockIdx.x;
  const int chunk = bid & 31;
  const int rb    = bid >> 5;
  const int tid   = threadIdx.x;
  const int lane  = tid & 63;
  const int w     = tid >> 6;
  const int r32   = lane & 31;
  const int h     = lane >> 5;
  const int iBase = rb * 256 + w * 64;

  __shared__ __align__(16) uint8_t lds[4][8192];

  // B fragments: this wave's two i-tiles, all of K=256, coalesced tiled loads.
  v8i b0[4], b1[4];
  const uint8_t* zb = Zi8 + (size_t)(rb * 8 + w * 2) * 8192 + lane * 16;
#pragma unroll
  for (int q = 0; q < 4; ++q) {
    union { int4 i4[2]; v8i v; } u0, u1;
    u0.i4[0] = *(const int4*)(zb + q * 2048);
    u0.i4[1] = *(const int4*)(zb + q * 2048 + 1024);
    u1.i4[0] = *(const int4*)(zb + 8192 + q * 2048);
    u1.i4[1] = *(const int4*)(zb + 8192 + q * 2048 + 1024);
    b0[q] = u0.v; b1[q] = u1.v;
  }
#pragma unroll
  for (int q = 0; q < 4; ++q) { asm("" : "+v"(b0[q])); asm("" : "+v"(b1[q])); }

  float m0 = -1e30f, l0 = 0.f, m1 = -1e30f, l1 = 0.f;

  const uint8_t* src = Zj8 + (size_t)chunk * (8 * 8192);  // 8 tiles = 256 cols

  stage8(src, &lds[0][0], tid);
  stage8(src + 8192, &lds[1][0], tid);

  for (int s = 0; s < 4; ++s) {
    __syncthreads();  // drains in-flight stages; reused bufs fully consumed
    if (s < 3) {
      stage8(src + (size_t)(2 * s + 2) * 8192, &lds[(2 * s + 2) & 3][0], tid);
      stage8(src + (size_t)(2 * s + 3) * 8192, &lds[(2 * s + 3) & 3][0], tid);
    }
#pragma unroll
    for (int sub = 0; sub < 2; ++sub) {
      const uint8_t* buf = &lds[(2 * s + sub) & 3][0] + lane * 16;
      f32x16 acc0 = {}, acc1 = {};
      __builtin_amdgcn_s_setprio(1);
#pragma unroll
      for (int q = 0; q < 4; ++q) {
        union { int4 i4[2]; v8i v; } ua;
        ua.i4[0] = *(const int4*)(buf + q * 2048);          // imm-offset reads,
        ua.i4[1] = *(const int4*)(buf + q * 2048 + 1024);   // conflict-free
        acc0 = __builtin_amdgcn_mfma_scale_f32_32x32x64_f8f6f4(
            ua.v, b0[q], acc0, 0, 0, 0, 0x7F7F7F7F, 0, 0x7F7F7F7F);
        acc1 = __builtin_amdgcn_mfma_scale_f32_32x32x64_f8f6f4(
            ua.v, b1[q], acc1, 0, 0, 0, 0x7F7F7F7F, 0, 0x7F7F7F7F);
      }
      __builtin_amdgcn_s_setprio(0);
      lse_update(acc0, m0, l0);
      lse_update(acc1, m1, l1);
    }
  }

  // lanes l and l+32 hold the same i with complementary j-subsets: one swap
#pragma unroll
  for (int p = 0; p < 2; ++p) {
    float m = p ? m1 : m0;
    float l = p ? l1 : l0;
    const float mo = __shfl_xor(m, 32);
    const float lo = __shfl_xor(l, 32);
    const float mn = fmaxf(m, mo);
    l = l * __builtin_amdgcn_exp2f(m - mn) + lo * __builtin_amdgcn_exp2f(mo - mn);
    if (h == 0) {
      const int i = iBase + p * 32 + r32;
      // log2-domain partial lse, [i][chunk] layout for coalesced finalize
      plse[(size_t)i * 32 + chunk] = mn + __builtin_amdgcn_logf(l);
    }
  }
}

// ---------- pass 3: per-row combine + grid reduction (last-block ticket) ---
__global__ __launch_bounds__(256) void finalize_kernel(
    const float* __restrict__ plse, const float* __restrict__ pos,
    float2* __restrict__ bpart, unsigned int* __restrict__ counter,
    float* __restrict__ out) {
  const int tid = threadIdx.x;
  const int row = blockIdx.x * 256 + tid;
  float v[32];
#pragma unroll
  for (int c = 0; c < 8; ++c) {
    const float4 q = ((const float4*)(plse + (size_t)row * 32))[c];
    v[c * 4 + 0] = q.x; v[c * 4 + 1] = q.y; v[c * 4 + 2] = q.z; v[c * 4 + 3] = q.w;
  }
  float M = v[0];
#pragma unroll
  for (int c = 1; c < 32; ++c) M = fmaxf(M, v[c]);
  float S = 0.0f;
#pragma unroll
  for (int c = 0; c < 32; ++c) S += __builtin_amdgcn_exp2f(v[c] - M);
  const float lse = LN2F * (M + __builtin_amdgcn_logf(S));  // natural-log lse
  const float pv  = pos[row];
  float lsum = lse - 1000.0f * pv;
  float psum = pv;
#pragma unroll
  for (int msk = 1; msk < 64; msk <<= 1) {
    lsum += __shfl_xor(lsum, msk);
    psum += __shfl_xor(psum, msk);
  }
  __shared__ float sl[4], sp[4];
  const int w = tid >> 6, lane = tid & 63;
  if (lane == 0) { sl[w] = lsum; sp[w] = psum; }
  __syncthreads();
  if (tid == 0) {
    union { float2 f; unsigned long long u; } pk;
    pk.f = make_float2(sl[0] + sl[1] + sl[2] + sl[3],
                       sp[0] + sp[1] + sp[2] + sp[3]);
    __hip_atomic_store((unsigned long long*)&bpart[blockIdx.x], pk.u,
                       __ATOMIC_RELEASE, __HIP_MEMORY_SCOPE_AGENT);
    const unsigned int t = __hip_atomic_fetch_add(
        counter, 1u, __ATOMIC_ACQ_REL, __HIP_MEMORY_SCOPE_AGENT);
    if (t == 31u) {  // last block: deterministic ordered reduce of 32 partials
      float L = 0.f, P = 0.f;
#pragma unroll
      for (int i = 0; i < 32; ++i) {
        union { float2 f; unsigned long long u; } q2;
        q2.u = __hip_atomic_load((const unsigned long long*)&bpart[i],
                                 __ATOMIC_ACQUIRE, __HIP_MEMORY_SCOPE_AGENT);
        L += q2.f.x; P += q2.f.y;
      }
      out[0] = L / (float)BATCH;  // loss
      out[1] = P;                 // sum(positives)
    }
  }
}

extern "C" void kernel_launch(void* const* d_in, const int* in_sizes, int n_in,
                              void* d_out, int out_size, void* d_ws, size_t ws_size,
                              hipStream_t stream) {
  const float* p1 = (const float*)d_in[0];
  const float* p2 = (const float*)d_in[1];
  float* out = (float*)d_out;
  uint8_t* ws = (uint8_t*)d_ws;

  uint8_t* Zi8          = ws;                                                  // 2 MB (tiled)
  uint8_t* Zj8          = ws + (size_t)2 * 1024 * 1024;                        // 2 MB (tiled)
  float* pos            = (float*)(ws + (size_t)4 * 1024 * 1024);              // 32 KB
  float2* bpart         = (float2*)(ws + (size_t)4 * 1024 * 1024 + 32 * 1024); // 256 B
  unsigned int* counter = (unsigned int*)(ws + (size_t)4 * 1024 * 1024 + 40 * 1024); // 4 B
  float* plse           = (float*)(ws + (size_t)4 * 1024 * 1024 + 64 * 1024);  // 1 MB

  hipMemsetAsync(counter, 0, sizeof(unsigned int), stream);
  prep_kernel<<<dim3(2048), dim3(256), 0, stream>>>(p1, p2, Zi8, Zj8, pos);
  lse_kernel<<<dim3(1024), dim3(256), 0, stream>>>(Zi8, Zj8, plse);
  finalize_kernel<<<dim3(32), dim3(256), 0, stream>>>(plse, pos, bpart, counter, out);
}

// Round 8
// 46.951 us; speedup vs baseline: 1.8431x; 1.8431x over previous
//
#include <hip/hip_runtime.h>
#include <hip/hip_fp8.h>
#include <stdint.h>
#include <stddef.h>

#define BATCH 8192
#define DIM   256

#define LN2F 0.6931471805599453f
// operand quantization scales; product = 1000*log2(e) = 1442.6950408889634
// so MFMA accs are directly exp2-domain scores (no dequant in hot loop).
#define SCALE_ZJ 16.0f                 // A side (staged)
#define SCALE_ZI 90.16844005556021f    // B side (regs)

typedef int   v8i    __attribute__((ext_vector_type(8)));   // 32B fp8 frag (8 VGPR)
typedef float f32x16 __attribute__((ext_vector_type(16)));  // 32x32 MFMA acc

// Fragment-slot-tiled layout for Zi8/Zj8 (tile = 32 rows x 256B = 8KB):
//   elem(row, kb) -> tile(row>>5)*8192 + q*2048 + c*1024 + (32h + (row&31))*16 + b
//   where kb = q*64 + h*32 + c*16 + b  (q<4, h<2, c<2, b<16).
// Slot index (32h + r32) == MFMA lane id, so:
//   - A-frag ds_read: one vaddr (lane*16) + imm offsets, conflict-free (R7: 0)
//   - staging: identity mapping, linear & fully coalesced
//   - B-frag global loads: lane*16 contiguous, fully coalesced.

// ---------- helpers ----------
static __device__ __forceinline__ uint8_t f2fp8(float f) {
  __hip_fp8_e4m3 q(f);                       // OCP e4m3fn, RNE+sat
  return *reinterpret_cast<uint8_t*>(&q);
}

// stage one 8KB tile: identity mapping (LDS offset == source offset)
static __device__ __forceinline__ void stage8(const uint8_t* __restrict__ src,
                                              uint8_t* dst, int tid) {
#pragma unroll
  for (int it = 0; it < 2; ++it) {
    const int off = it * 4096 + tid * 16;
    __builtin_amdgcn_global_load_lds(
        (const __attribute__((address_space(1))) void*)(src + off),
        (__attribute__((address_space(3))) void*)(dst + off),
        16, 0, 0);
  }
}

// ---------- pass 1: normalize, exact fp32 positives, tiled fp8 store -------
__global__ __launch_bounds__(256) void prep_kernel(
    const float* __restrict__ p1, const float* __restrict__ p2,
    uint8_t* __restrict__ Zi8, uint8_t* __restrict__ Zj8,
    float* __restrict__ pos) {
  const int lane = threadIdx.x & 63;
  const int w    = threadIdx.x >> 6;
  const int row  = blockIdx.x * 4 + w;   // one wave per row

  const float4 x1 = ((const float4*)p1)[row * 64 + lane];
  const float4 x2 = ((const float4*)p2)[row * 64 + lane];
  float ss1 = x1.x * x1.x + x1.y * x1.y + x1.z * x1.z + x1.w * x1.w;
  float ss2 = x2.x * x2.x + x2.y * x2.y + x2.z * x2.z + x2.w * x2.w;
  float d   = x1.x * x2.x + x1.y * x2.y + x1.z * x2.z + x1.w * x2.w;
#pragma unroll
  for (int m = 1; m < 64; m <<= 1) {
    ss1 += __shfl_xor(ss1, m);
    ss2 += __shfl_xor(ss2, m);
    d   += __shfl_xor(d, m);
  }
  const float n1 = fmaxf(sqrtf(ss1), 1e-12f);
  const float n2 = fmaxf(sqrtf(ss2), 1e-12f);
  if (lane == 0) pos[row] = d / (n1 * n2);          // exact fp32 diagonal

  const float sI = SCALE_ZI / n1;
  const float sJ = SCALE_ZJ / n2;
  uchar4 u1, u2;
  u1.x = f2fp8(x1.x * sI); u1.y = f2fp8(x1.y * sI);
  u1.z = f2fp8(x1.z * sI); u1.w = f2fp8(x1.w * sI);
  u2.x = f2fp8(x2.x * sJ); u2.y = f2fp8(x2.y * sJ);
  u2.z = f2fp8(x2.z * sJ); u2.w = f2fp8(x2.w * sJ);

  // lane holds kb = 4*lane .. 4*lane+3 -> tiled address
  const size_t tb = (size_t)(row >> 5) * 8192;
  const int off = (lane >> 4) * 2048 + ((lane >> 2) & 1) * 1024 +
                  (((lane >> 3) & 1) * 32 + (row & 31)) * 16 + (lane & 3) * 4;
  *(uchar4*)(Zi8 + tb + off) = u1;
  *(uchar4*)(Zj8 + tb + off) = u2;
}

// ---------- online lse update for one 16-score acc block (lean temps) ------
static __device__ __forceinline__ void lse_update(const f32x16& acc,
                                                  float& m, float& l) {
  float t0 = fmaxf(fmaxf(acc[0],  acc[1]),  acc[2]);
  float t1 = fmaxf(fmaxf(acc[3],  acc[4]),  acc[5]);
  float t2 = fmaxf(fmaxf(acc[6],  acc[7]),  acc[8]);
  float t3 = fmaxf(fmaxf(acc[9],  acc[10]), acc[11]);
  t0 = fmaxf(fmaxf(t0, t1), fmaxf(fmaxf(acc[12], acc[13]), acc[14]));
  t2 = fmaxf(fmaxf(t2, t3), acc[15]);
  const float mn = fmaxf(m, fmaxf(t0, t2));
  float s0 = 0.f, s1 = 0.f;
#pragma unroll
  for (int r = 0; r < 16; r += 2) {
    s0 += __builtin_amdgcn_exp2f(acc[r + 0] - mn);
    s1 += __builtin_amdgcn_exp2f(acc[r + 1] - mn);
  }
  l = l * __builtin_amdgcn_exp2f(m - mn) + (s0 + s1);
  m = mn;
}

// ---------- pass 2: fused fp8 MFMA GEMM + online logsumexp ----------
// acc = mfma_scale_32x32x64(A=Zj_frag, B=Zi_frag, unit scales) -> D[j][i],
// col(lane&31)=i. Each lane owns TWO i rows; scalar (m,l) per row.
// grid = 32 row-blocks (256 i) x 32 j-chunks (256 cols); chunk = bid&31 so
// same-chunk blocks share an XCD (bid%8 == chunk%8), Zj slice L2-local.
// launch_bounds(256,3): R5/R7 post-mortem — min-waves=4 makes the allocator
// clamp to the 64-VGPR step and spill accs to scratch (FETCH/WRITE ~100+ MB,
// MfmaUtil 8%). With 3, it allocates ~140-168 regs spill-free (R6: fast).
__global__ __launch_bounds__(256, 3) void lse_kernel(
    const uint8_t* __restrict__ Zi8, const uint8_t* __restrict__ Zj8,
    float* __restrict__ plse) {
  const int bid   = blockIdx.x;
  const int chunk = bid & 31;
  const int rb    = bid >> 5;
  const int tid   = threadIdx.x;
  const int lane  = tid & 63;
  const int w     = tid >> 6;
  const int r32   = lane & 31;
  const int h     = lane >> 5;
  const int iBase = rb * 256 + w * 64;

  __shared__ __align__(16) uint8_t lds[4][8192];

  // B fragments: this wave's two i-tiles, all of K=256, coalesced tiled loads.
  v8i b0[4], b1[4];
  const uint8_t* zb = Zi8 + (size_t)(rb * 8 + w * 2) * 8192 + lane * 16;
#pragma unroll
  for (int q = 0; q < 4; ++q) {
    union { int4 i4[2]; v8i v; } u0, u1;
    u0.i4[0] = *(const int4*)(zb + q * 2048);
    u0.i4[1] = *(const int4*)(zb + q * 2048 + 1024);
    u1.i4[0] = *(const int4*)(zb + 8192 + q * 2048);
    u1.i4[1] = *(const int4*)(zb + 8192 + q * 2048 + 1024);
    b0[q] = u0.v; b1[q] = u1.v;
  }
#pragma unroll
  for (int q = 0; q < 4; ++q) { asm("" : "+v"(b0[q])); asm("" : "+v"(b1[q])); }

  float m0 = -1e30f, l0 = 0.f, m1 = -1e30f, l1 = 0.f;

  const uint8_t* src = Zj8 + (size_t)chunk * (8 * 8192);  // 8 tiles = 256 cols

  stage8(src, &lds[0][0], tid);
  stage8(src + 8192, &lds[1][0], tid);

  for (int s = 0; s < 4; ++s) {
    __syncthreads();  // drains in-flight stages; reused bufs fully consumed
    if (s < 3) {
      stage8(src + (size_t)(2 * s + 2) * 8192, &lds[(2 * s + 2) & 3][0], tid);
      stage8(src + (size_t)(2 * s + 3) * 8192, &lds[(2 * s + 3) & 3][0], tid);
    }
#pragma unroll
    for (int sub = 0; sub < 2; ++sub) {
      const uint8_t* buf = &lds[(2 * s + sub) & 3][0] + lane * 16;
      f32x16 acc0 = {}, acc1 = {};
      __builtin_amdgcn_s_setprio(1);
#pragma unroll
      for (int q = 0; q < 4; ++q) {
        union { int4 i4[2]; v8i v; } ua;
        ua.i4[0] = *(const int4*)(buf + q * 2048);          // imm-offset reads,
        ua.i4[1] = *(const int4*)(buf + q * 2048 + 1024);   // conflict-free
        acc0 = __builtin_amdgcn_mfma_scale_f32_32x32x64_f8f6f4(
            ua.v, b0[q], acc0, 0, 0, 0, 0x7F7F7F7F, 0, 0x7F7F7F7F);
        acc1 = __builtin_amdgcn_mfma_scale_f32_32x32x64_f8f6f4(
            ua.v, b1[q], acc1, 0, 0, 0, 0x7F7F7F7F, 0, 0x7F7F7F7F);
      }
      __builtin_amdgcn_s_setprio(0);
      lse_update(acc0, m0, l0);
      lse_update(acc1, m1, l1);
    }
  }

  // lanes l and l+32 hold the same i with complementary j-subsets: one swap
#pragma unroll
  for (int p = 0; p < 2; ++p) {
    float m = p ? m1 : m0;
    float l = p ? l1 : l0;
    const float mo = __shfl_xor(m, 32);
    const float lo = __shfl_xor(l, 32);
    const float mn = fmaxf(m, mo);
    l = l * __builtin_amdgcn_exp2f(m - mn) + lo * __builtin_amdgcn_exp2f(mo - mn);
    if (h == 0) {
      const int i = iBase + p * 32 + r32;
      // log2-domain partial lse, [i][chunk] layout for coalesced finalize
      plse[(size_t)i * 32 + chunk] = mn + __builtin_amdgcn_logf(l);
    }
  }
}

// ---------- pass 3: per-row combine + grid reduction (last-block ticket) ---
__global__ __launch_bounds__(256) void finalize_kernel(
    const float* __restrict__ plse, const float* __restrict__ pos,
    float2* __restrict__ bpart, unsigned int* __restrict__ counter,
    float* __restrict__ out) {
  const int tid = threadIdx.x;
  const int row = blockIdx.x * 256 + tid;
  float v[32];
#pragma unroll
  for (int c = 0; c < 8; ++c) {
    const float4 q = ((const float4*)(plse + (size_t)row * 32))[c];
    v[c * 4 + 0] = q.x; v[c * 4 + 1] = q.y; v[c * 4 + 2] = q.z; v[c * 4 + 3] = q.w;
  }
  float M = v[0];
#pragma unroll
  for (int c = 1; c < 32; ++c) M = fmaxf(M, v[c]);
  float S = 0.0f;
#pragma unroll
  for (int c = 0; c < 32; ++c) S += __builtin_amdgcn_exp2f(v[c] - M);
  const float lse = LN2F * (M + __builtin_amdgcn_logf(S));  // natural-log lse
  const float pv  = pos[row];
  float lsum = lse - 1000.0f * pv;
  float psum = pv;
#pragma unroll
  for (int msk = 1; msk < 64; msk <<= 1) {
    lsum += __shfl_xor(lsum, msk);
    psum += __shfl_xor(psum, msk);
  }
  __shared__ float sl[4], sp[4];
  const int w = tid >> 6, lane = tid & 63;
  if (lane == 0) { sl[w] = lsum; sp[w] = psum; }
  __syncthreads();
  if (tid == 0) {
    union { float2 f; unsigned long long u; } pk;
    pk.f = make_float2(sl[0] + sl[1] + sl[2] + sl[3],
                       sp[0] + sp[1] + sp[2] + sp[3]);
    __hip_atomic_store((unsigned long long*)&bpart[blockIdx.x], pk.u,
                       __ATOMIC_RELEASE, __HIP_MEMORY_SCOPE_AGENT);
    const unsigned int t = __hip_atomic_fetch_add(
        counter, 1u, __ATOMIC_ACQ_REL, __HIP_MEMORY_SCOPE_AGENT);
    if (t == 31u) {  // last block: deterministic ordered reduce of 32 partials
      float L = 0.f, P = 0.f;
#pragma unroll
      for (int i = 0; i < 32; ++i) {
        union { float2 f; unsigned long long u; } q2;
        q2.u = __hip_atomic_load((const unsigned long long*)&bpart[i],
                                 __ATOMIC_ACQUIRE, __HIP_MEMORY_SCOPE_AGENT);
        L += q2.f.x; P += q2.f.y;
      }
      out[0] = L / (float)BATCH;  // loss
      out[1] = P;                 // sum(positives)
    }
  }
}

extern "C" void kernel_launch(void* const* d_in, const int* in_sizes, int n_in,
                              void* d_out, int out_size, void* d_ws, size_t ws_size,
                              hipStream_t stream) {
  const float* p1 = (const float*)d_in[0];
  const float* p2 = (const float*)d_in[1];
  float* out = (float*)d_out;
  uint8_t* ws = (uint8_t*)d_ws;

  uint8_t* Zi8          = ws;                                                  // 2 MB (tiled)
  uint8_t* Zj8          = ws + (size_t)2 * 1024 * 1024;                        // 2 MB (tiled)
  float* pos            = (float*)(ws + (size_t)4 * 1024 * 1024);              // 32 KB
  float2* bpart         = (float2*)(ws + (size_t)4 * 1024 * 1024 + 32 * 1024); // 256 B
  unsigned int* counter = (unsigned int*)(ws + (size_t)4 * 1024 * 1024 + 40 * 1024); // 4 B
  float* plse           = (float*)(ws + (size_t)4 * 1024 * 1024 + 64 * 1024);  // 1 MB

  hipMemsetAsync(counter, 0, sizeof(unsigned int), stream);
  prep_kernel<<<dim3(2048), dim3(256), 0, stream>>>(p1, p2, Zi8, Zj8, pos);
  lse_kernel<<<dim3(1024), dim3(256), 0, stream>>>(Zi8, Zj8, plse);
  finalize_kernel<<<dim3(32), dim3(256), 0, stream>>>(plse, pos, bpart, counter, out);
}

// Round 9
// 46.792 us; speedup vs baseline: 1.8494x; 1.0034x over previous
//
#include <hip/hip_runtime.h>
#include <hip/hip_fp8.h>
#include <stdint.h>
#include <stddef.h>

#define BATCH 8192
#define DIM   256

#define LN2F 0.6931471805599453f
// operand quantization scales; product = 1000*log2(e) = 1442.6950408889634
// so MFMA accs are directly exp2-domain scores (no dequant in hot loop).
#define SCALE_ZJ 16.0f                 // A side (staged)
#define SCALE_ZI 90.16844005556021f    // B side (regs)

typedef int   v8i    __attribute__((ext_vector_type(8)));   // 32B fp8 frag (8 VGPR)
typedef float f32x16 __attribute__((ext_vector_type(16)));  // 32x32 MFMA acc

// Fragment-slot-tiled layout for Zi8/Zj8 (tile = 32 rows x 256B = 8KB):
//   elem(row, kb) -> tile(row>>5)*8192 + q*2048 + c*1024 + (32h + (row&31))*16 + b
//   where kb = q*64 + h*32 + c*16 + b  (q<4, h<2, c<2, b<16).
// Slot index (32h + r32) == MFMA lane id, so:
//   - A-frag ds_read: one vaddr (lane*16) + imm offsets, conflict-free (R7: 0)
//   - staging: identity mapping, linear & fully coalesced
//   - B-frag global loads: lane*16 contiguous, fully coalesced.

// ---------- helpers ----------
static __device__ __forceinline__ uint8_t f2fp8(float f) {
  __hip_fp8_e4m3 q(f);                       // OCP e4m3fn, RNE+sat
  return *reinterpret_cast<uint8_t*>(&q);
}

// ---------- pass 1: normalize, exact fp32 positives, tiled fp8 store -------
__global__ __launch_bounds__(256) void prep_kernel(
    const float* __restrict__ p1, const float* __restrict__ p2,
    uint8_t* __restrict__ Zi8, uint8_t* __restrict__ Zj8,
    float* __restrict__ pos) {
  const int lane = threadIdx.x & 63;
  const int w    = threadIdx.x >> 6;
  const int row  = blockIdx.x * 4 + w;   // one wave per row

  const float4 x1 = ((const float4*)p1)[row * 64 + lane];
  const float4 x2 = ((const float4*)p2)[row * 64 + lane];
  float ss1 = x1.x * x1.x + x1.y * x1.y + x1.z * x1.z + x1.w * x1.w;
  float ss2 = x2.x * x2.x + x2.y * x2.y + x2.z * x2.z + x2.w * x2.w;
  float d   = x1.x * x2.x + x1.y * x2.y + x1.z * x2.z + x1.w * x2.w;
#pragma unroll
  for (int m = 1; m < 64; m <<= 1) {
    ss1 += __shfl_xor(ss1, m);
    ss2 += __shfl_xor(ss2, m);
    d   += __shfl_xor(d, m);
  }
  const float n1 = fmaxf(sqrtf(ss1), 1e-12f);
  const float n2 = fmaxf(sqrtf(ss2), 1e-12f);
  if (lane == 0) pos[row] = d / (n1 * n2);          // exact fp32 diagonal

  const float sI = SCALE_ZI / n1;
  const float sJ = SCALE_ZJ / n2;
  uchar4 u1, u2;
  u1.x = f2fp8(x1.x * sI); u1.y = f2fp8(x1.y * sI);
  u1.z = f2fp8(x1.z * sI); u1.w = f2fp8(x1.w * sI);
  u2.x = f2fp8(x2.x * sJ); u2.y = f2fp8(x2.y * sJ);
  u2.z = f2fp8(x2.z * sJ); u2.w = f2fp8(x2.w * sJ);

  // lane holds kb = 4*lane .. 4*lane+3 -> tiled address
  const size_t tb = (size_t)(row >> 5) * 8192;
  const int off = (lane >> 4) * 2048 + ((lane >> 2) & 1) * 1024 +
                  (((lane >> 3) & 1) * 32 + (row & 31)) * 16 + (lane & 3) * 4;
  *(uchar4*)(Zi8 + tb + off) = u1;
  *(uchar4*)(Zj8 + tb + off) = u2;
}

// ---------- online lse update for one 16-score acc block (lean temps) ------
static __device__ __forceinline__ void lse_update(const f32x16& acc,
                                                  float& m, float& l) {
  float t0 = fmaxf(fmaxf(acc[0],  acc[1]),  acc[2]);
  float t1 = fmaxf(fmaxf(acc[3],  acc[4]),  acc[5]);
  float t2 = fmaxf(fmaxf(acc[6],  acc[7]),  acc[8]);
  float t3 = fmaxf(fmaxf(acc[9],  acc[10]), acc[11]);
  t0 = fmaxf(fmaxf(t0, t1), fmaxf(fmaxf(acc[12], acc[13]), acc[14]));
  t2 = fmaxf(fmaxf(t2, t3), acc[15]);
  const float mn = fmaxf(m, fmaxf(t0, t2));
  float s0 = 0.f, s1 = 0.f;
#pragma unroll
  for (int r = 0; r < 16; r += 2) {
    s0 += __builtin_amdgcn_exp2f(acc[r + 0] - mn);
    s1 += __builtin_amdgcn_exp2f(acc[r + 1] - mn);
  }
  l = l * __builtin_amdgcn_exp2f(m - mn) + (s0 + s1);
  m = mn;
}

// ---------- pass 2: fused fp8 MFMA GEMM + online logsumexp ----------
// acc = mfma_scale_32x32x64(A=Zj_frag, B=Zi_frag, unit scales) -> D[j][i],
// col(lane&31)=i. Each lane owns TWO i rows; scalar (m,l) per row.
// grid = 32 row-blocks (256 i) x 32 j-chunks (256 cols); chunk = bid&31 so
// same-chunk blocks share an XCD (bid%8 == chunk%8), Zj slice L2-local.
// Whole 64KB chunk staged into LDS once (2-phase: tiles 0-3, then 4-7 issued
// behind the first barrier) -> only 2 __syncthreads per block, compute is
// sync-free. LDS 64KB => exactly 2 blocks/CU resident; grid = 4 blocks/CU
// runs as two clean rounds (R8 post-mortem: 3-resident + lone-block tail).
// launch_bounds(256,2): relaxed reg cap kills the R5/R7 spill trap.
__global__ __launch_bounds__(256, 2) void lse_kernel(
    const uint8_t* __restrict__ Zi8, const uint8_t* __restrict__ Zj8,
    float* __restrict__ plse) {
  const int bid   = blockIdx.x;
  const int chunk = bid & 31;
  const int rb    = bid >> 5;
  const int tid   = threadIdx.x;
  const int lane  = tid & 63;
  const int r32   = lane & 31;
  const int h     = lane >> 5;
  const int w     = tid >> 6;
  const int iBase = rb * 256 + w * 64;

  __shared__ __align__(16) uint8_t lds[65536];  // full 256-col chunk (8 tiles)

  const uint8_t* src = Zj8 + (size_t)chunk * 65536;

  // stage tiles 0-3 (identity mapping: uniform base, HW adds lane*16)
#pragma unroll
  for (int it = 0; it < 8; ++it) {
    const int off = it * 4096 + tid * 16;
    __builtin_amdgcn_global_load_lds(
        (const __attribute__((address_space(1))) void*)(src + off),
        (__attribute__((address_space(3))) void*)(lds + off), 16, 0, 0);
  }

  // B fragments: this wave's two i-tiles, all of K=256, coalesced tiled loads.
  v8i b0[4], b1[4];
  const uint8_t* zb = Zi8 + (size_t)(rb * 8 + w * 2) * 8192 + lane * 16;
#pragma unroll
  for (int q = 0; q < 4; ++q) {
    union { int4 i4[2]; v8i v; } u0, u1;
    u0.i4[0] = *(const int4*)(zb + q * 2048);
    u0.i4[1] = *(const int4*)(zb + q * 2048 + 1024);
    u1.i4[0] = *(const int4*)(zb + 8192 + q * 2048);
    u1.i4[1] = *(const int4*)(zb + 8192 + q * 2048 + 1024);
    b0[q] = u0.v; b1[q] = u1.v;
  }
#pragma unroll
  for (int q = 0; q < 4; ++q) { asm("" : "+v"(b0[q])); asm("" : "+v"(b1[q])); }

  float m0 = -1e30f, l0 = 0.f, m1 = -1e30f, l1 = 0.f;

  __syncthreads();  // tiles 0-3 resident (drains own vmcnt + block barrier)

  // issue stage of tiles 4-7; loads complete under tiles-0-3 compute
#pragma unroll
  for (int it = 8; it < 16; ++it) {
    const int off = it * 4096 + tid * 16;
    __builtin_amdgcn_global_load_lds(
        (const __attribute__((address_space(1))) void*)(src + off),
        (__attribute__((address_space(3))) void*)(lds + off), 16, 0, 0);
  }
  asm volatile("" ::: "memory");  // keep the stage issue above the compute

#pragma unroll
  for (int half = 0; half < 2; ++half) {
    if (half == 1) __syncthreads();  // tiles 4-7 resident
#pragma unroll
    for (int t = 0; t < 4; ++t) {
      const uint8_t* buf = lds + (half * 4 + t) * 8192 + lane * 16;
      f32x16 acc0 = {}, acc1 = {};
      __builtin_amdgcn_s_setprio(1);
#pragma unroll
      for (int q = 0; q < 4; ++q) {
        union { int4 i4[2]; v8i v; } ua;
        ua.i4[0] = *(const int4*)(buf + q * 2048);          // imm-offset reads,
        ua.i4[1] = *(const int4*)(buf + q * 2048 + 1024);   // conflict-free
        acc0 = __builtin_amdgcn_mfma_scale_f32_32x32x64_f8f6f4(
            ua.v, b0[q], acc0, 0, 0, 0, 0x7F7F7F7F, 0, 0x7F7F7F7F);
        acc1 = __builtin_amdgcn_mfma_scale_f32_32x32x64_f8f6f4(
            ua.v, b1[q], acc1, 0, 0, 0, 0x7F7F7F7F, 0, 0x7F7F7F7F);
      }
      __builtin_amdgcn_s_setprio(0);
      lse_update(acc0, m0, l0);
      lse_update(acc1, m1, l1);
    }
  }

  // lanes l and l+32 hold the same i with complementary j-subsets: one swap
#pragma unroll
  for (int p = 0; p < 2; ++p) {
    float m = p ? m1 : m0;
    float l = p ? l1 : l0;
    const float mo = __shfl_xor(m, 32);
    const float lo = __shfl_xor(l, 32);
    const float mn = fmaxf(m, mo);
    l = l * __builtin_amdgcn_exp2f(m - mn) + lo * __builtin_amdgcn_exp2f(mo - mn);
    if (h == 0) {
      const int i = iBase + p * 32 + r32;
      // log2-domain partial lse, [i][chunk] layout for coalesced finalize
      plse[(size_t)i * 32 + chunk] = mn + __builtin_amdgcn_logf(l);
    }
  }
}

// ---------- pass 3: per-row combine + grid reduction (last-block ticket) ---
__global__ __launch_bounds__(256) void finalize_kernel(
    const float* __restrict__ plse, const float* __restrict__ pos,
    float2* __restrict__ bpart, unsigned int* __restrict__ counter,
    float* __restrict__ out) {
  const int tid = threadIdx.x;
  const int row = blockIdx.x * 256 + tid;
  float v[32];
#pragma unroll
  for (int c = 0; c < 8; ++c) {
    const float4 q = ((const float4*)(plse + (size_t)row * 32))[c];
    v[c * 4 + 0] = q.x; v[c * 4 + 1] = q.y; v[c * 4 + 2] = q.z; v[c * 4 + 3] = q.w;
  }
  float M = v[0];
#pragma unroll
  for (int c = 1; c < 32; ++c) M = fmaxf(M, v[c]);
  float S = 0.0f;
#pragma unroll
  for (int c = 0; c < 32; ++c) S += __builtin_amdgcn_exp2f(v[c] - M);
  const float lse = LN2F * (M + __builtin_amdgcn_logf(S));  // natural-log lse
  const float pv  = pos[row];
  float lsum = lse - 1000.0f * pv;
  float psum = pv;
#pragma unroll
  for (int msk = 1; msk < 64; msk <<= 1) {
    lsum += __shfl_xor(lsum, msk);
    psum += __shfl_xor(psum, msk);
  }
  __shared__ float sl[4], sp[4];
  const int w = tid >> 6, lane = tid & 63;
  if (lane == 0) { sl[w] = lsum; sp[w] = psum; }
  __syncthreads();
  if (tid == 0) {
    union { float2 f; unsigned long long u; } pk;
    pk.f = make_float2(sl[0] + sl[1] + sl[2] + sl[3],
                       sp[0] + sp[1] + sp[2] + sp[3]);
    __hip_atomic_store((unsigned long long*)&bpart[blockIdx.x], pk.u,
                       __ATOMIC_RELEASE, __HIP_MEMORY_SCOPE_AGENT);
    const unsigned int t = __hip_atomic_fetch_add(
        counter, 1u, __ATOMIC_ACQ_REL, __HIP_MEMORY_SCOPE_AGENT);
    if (t == 31u) {  // last block: deterministic ordered reduce of 32 partials
      float L = 0.f, P = 0.f;
#pragma unroll
      for (int i = 0; i < 32; ++i) {
        union { float2 f; unsigned long long u; } q2;
        q2.u = __hip_atomic_load((const unsigned long long*)&bpart[i],
                                 __ATOMIC_ACQUIRE, __HIP_MEMORY_SCOPE_AGENT);
        L += q2.f.x; P += q2.f.y;
      }
      out[0] = L / (float)BATCH;  // loss
      out[1] = P;                 // sum(positives)
    }
  }
}

extern "C" void kernel_launch(void* const* d_in, const int* in_sizes, int n_in,
                              void* d_out, int out_size, void* d_ws, size_t ws_size,
                              hipStream_t stream) {
  const float* p1 = (const float*)d_in[0];
  const float* p2 = (const float*)d_in[1];
  float* out = (float*)d_out;
  uint8_t* ws = (uint8_t*)d_ws;

  uint8_t* Zi8          = ws;                                                  // 2 MB (tiled)
  uint8_t* Zj8          = ws + (size_t)2 * 1024 * 1024;                        // 2 MB (tiled)
  float* pos            = (float*)(ws + (size_t)4 * 1024 * 1024);              // 32 KB
  float2* bpart         = (float2*)(ws + (size_t)4 * 1024 * 1024 + 32 * 1024); // 256 B
  unsigned int* counter = (unsigned int*)(ws + (size_t)4 * 1024 * 1024 + 40 * 1024); // 4 B
  float* plse           = (float*)(ws + (size_t)4 * 1024 * 1024 + 64 * 1024);  // 1 MB

  hipMemsetAsync(counter, 0, sizeof(unsigned int), stream);
  prep_kernel<<<dim3(2048), dim3(256), 0, stream>>>(p1, p2, Zi8, Zj8, pos);
  lse_kernel<<<dim3(1024), dim3(256), 0, stream>>>(Zi8, Zj8, plse);
  finalize_kernel<<<dim3(32), dim3(256), 0, stream>>>(plse, pos, bpart, counter, out);
}

// Round 10
// 46.113 us; speedup vs baseline: 1.8767x; 1.0147x over previous
//
#include <hip/hip_runtime.h>
#include <hip/hip_fp8.h>
#include <stdint.h>
#include <stddef.h>

#define BATCH 8192
#define DIM   256

#define LN2F 0.6931471805599453f
// operand quantization scales; product = 1000*log2(e) = 1442.6950408889634
// so MFMA accs are directly exp2-domain scores (no dequant in hot loop).
#define SCALE_ZJ 16.0f                 // A side (staged)
#define SCALE_ZI 90.16844005556021f    // B side (regs)

typedef int   v8i    __attribute__((ext_vector_type(8)));   // 32B fp8 frag (8 VGPR)
typedef float f32x16 __attribute__((ext_vector_type(16)));  // 32x32 MFMA acc

// Fragment-slot-tiled layout for Zi8/Zj8 (tile = 32 rows x 256B = 8KB):
//   elem(row, kb) -> tile(row>>5)*8192 + q*2048 + c*1024 + (32h + (row&31))*16 + b
//   where kb = q*64 + h*32 + c*16 + b  (q<4, h<2, c<2, b<16).
// Slot index (32h + r32) == MFMA lane id, so:
//   - A-frag ds_read: one vaddr (lane*16) + imm offsets, conflict-free (R7: 0)
//   - staging: identity mapping, linear & fully coalesced
//   - B-frag global loads: lane*16 contiguous, fully coalesced.

// ---------- helpers ----------
static __device__ __forceinline__ uint8_t f2fp8(float f) {
  __hip_fp8_e4m3 q(f);                       // OCP e4m3fn, RNE+sat
  return *reinterpret_cast<uint8_t*>(&q);
}

// ---------- pass 1: normalize, exact fp32 positives, tiled fp8 store -------
__global__ __launch_bounds__(256) void prep_kernel(
    const float* __restrict__ p1, const float* __restrict__ p2,
    uint8_t* __restrict__ Zi8, uint8_t* __restrict__ Zj8,
    float* __restrict__ pos) {
  const int lane = threadIdx.x & 63;
  const int w    = threadIdx.x >> 6;
  const int row  = blockIdx.x * 4 + w;   // one wave per row

  const float4 x1 = ((const float4*)p1)[row * 64 + lane];
  const float4 x2 = ((const float4*)p2)[row * 64 + lane];
  float ss1 = x1.x * x1.x + x1.y * x1.y + x1.z * x1.z + x1.w * x1.w;
  float ss2 = x2.x * x2.x + x2.y * x2.y + x2.z * x2.z + x2.w * x2.w;
  float d   = x1.x * x2.x + x1.y * x2.y + x1.z * x2.z + x1.w * x2.w;
#pragma unroll
  for (int m = 1; m < 64; m <<= 1) {
    ss1 += __shfl_xor(ss1, m);
    ss2 += __shfl_xor(ss2, m);
    d   += __shfl_xor(d, m);
  }
  const float n1 = fmaxf(sqrtf(ss1), 1e-12f);
  const float n2 = fmaxf(sqrtf(ss2), 1e-12f);
  if (lane == 0) pos[row] = d / (n1 * n2);          // exact fp32 diagonal

  const float sI = SCALE_ZI / n1;
  const float sJ = SCALE_ZJ / n2;
  uchar4 u1, u2;
  u1.x = f2fp8(x1.x * sI); u1.y = f2fp8(x1.y * sI);
  u1.z = f2fp8(x1.z * sI); u1.w = f2fp8(x1.w * sI);
  u2.x = f2fp8(x2.x * sJ); u2.y = f2fp8(x2.y * sJ);
  u2.z = f2fp8(x2.z * sJ); u2.w = f2fp8(x2.w * sJ);

  // lane holds kb = 4*lane .. 4*lane+3 -> tiled address
  const size_t tb = (size_t)(row >> 5) * 8192;
  const int off = (lane >> 4) * 2048 + ((lane >> 2) & 1) * 1024 +
                  (((lane >> 3) & 1) * 32 + (row & 31)) * 16 + (lane & 3) * 4;
  *(uchar4*)(Zi8 + tb + off) = u1;
  *(uchar4*)(Zj8 + tb + off) = u2;
}

// ---------- online lse update for one 16-score acc block (lean temps) ------
static __device__ __forceinline__ void lse_update(const f32x16& acc,
                                                  float& m, float& l) {
  float t0 = fmaxf(fmaxf(acc[0],  acc[1]),  acc[2]);
  float t1 = fmaxf(fmaxf(acc[3],  acc[4]),  acc[5]);
  float t2 = fmaxf(fmaxf(acc[6],  acc[7]),  acc[8]);
  float t3 = fmaxf(fmaxf(acc[9],  acc[10]), acc[11]);
  t0 = fmaxf(fmaxf(t0, t1), fmaxf(fmaxf(acc[12], acc[13]), acc[14]));
  t2 = fmaxf(fmaxf(t2, t3), acc[15]);
  const float mn = fmaxf(m, fmaxf(t0, t2));
  float s0 = 0.f, s1 = 0.f;
#pragma unroll
  for (int r = 0; r < 16; r += 2) {
    s0 += __builtin_amdgcn_exp2f(acc[r + 0] - mn);
    s1 += __builtin_amdgcn_exp2f(acc[r + 1] - mn);
  }
  l = l * __builtin_amdgcn_exp2f(m - mn) + (s0 + s1);
  m = mn;
}

// ---------- pass 2: fused fp8 MFMA GEMM + online logsumexp ----------
// acc = mfma_scale_32x32x64(A=Zj_frag, B=Zi_frag, unit scales) -> D[j][i],
// col(lane&31)=i. Each lane owns TWO i rows; scalar (m,l) per row.
// grid = 32 row-blocks (256 i) x 64 j-chunks (128 cols = 4 tiles = 32KB).
// chunk = bid&63 -> same-chunk blocks share an XCD (bid%8 == chunk%8).
// Schedule: stage ALL 4 tiles + b-frag loads -> ONE __syncthreads -> fully
// sync-free compute (no lockstep drains). 32KB LDS + (256,3) => 3 blocks/CU
// resident; 2048 fine-grained blocks (8/CU) overlap stage with other blocks'
// compute and shrink the straggler tail (R8/R9 post-mortem: occupancy 2 and
// the 4-over-3 tail cost ~7us; barriers were not the binding constraint).
// No setprio: at 3 waves/SIMD it starves co-resident waves' VALU (m190).
__global__ __launch_bounds__(256, 3) void lse_kernel(
    const uint8_t* __restrict__ Zi8, const uint8_t* __restrict__ Zj8,
    float* __restrict__ plse) {
  const int bid   = blockIdx.x;
  const int chunk = bid & 63;
  const int rb    = bid >> 6;
  const int tid   = threadIdx.x;
  const int lane  = tid & 63;
  const int r32   = lane & 31;
  const int h     = lane >> 5;
  const int w     = tid >> 6;
  const int iBase = rb * 256 + w * 64;

  __shared__ __align__(16) uint8_t lds[32768];  // 4 tiles = 128 j-cols

  const uint8_t* src = Zj8 + (size_t)chunk * 32768;
  // stage all 4 tiles (identity mapping: uniform base, HW adds lane*16)
#pragma unroll
  for (int it = 0; it < 8; ++it) {
    const int off = it * 4096 + tid * 16;
    __builtin_amdgcn_global_load_lds(
        (const __attribute__((address_space(1))) void*)(src + off),
        (__attribute__((address_space(3))) void*)(lds + off), 16, 0, 0);
  }

  // B fragments: this wave's two i-tiles, all of K=256, coalesced tiled loads.
  v8i b0[4], b1[4];
  const uint8_t* zb = Zi8 + (size_t)(rb * 8 + w * 2) * 8192 + lane * 16;
#pragma unroll
  for (int q = 0; q < 4; ++q) {
    union { int4 i4[2]; v8i v; } u0, u1;
    u0.i4[0] = *(const int4*)(zb + q * 2048);
    u0.i4[1] = *(const int4*)(zb + q * 2048 + 1024);
    u1.i4[0] = *(const int4*)(zb + 8192 + q * 2048);
    u1.i4[1] = *(const int4*)(zb + 8192 + q * 2048 + 1024);
    b0[q] = u0.v; b1[q] = u1.v;
  }
#pragma unroll
  for (int q = 0; q < 4; ++q) { asm("" : "+v"(b0[q])); asm("" : "+v"(b1[q])); }

  float m0 = -1e30f, l0 = 0.f, m1 = -1e30f, l1 = 0.f;

  __syncthreads();  // single barrier: all tiles + b-frags resident

#pragma unroll
  for (int t = 0; t < 4; ++t) {
    const uint8_t* buf = lds + t * 8192 + lane * 16;
    f32x16 acc0 = {}, acc1 = {};
#pragma unroll
    for (int q = 0; q < 4; ++q) {
      union { int4 i4[2]; v8i v; } ua;
      ua.i4[0] = *(const int4*)(buf + q * 2048);          // imm-offset reads,
      ua.i4[1] = *(const int4*)(buf + q * 2048 + 1024);   // conflict-free
      acc0 = __builtin_amdgcn_mfma_scale_f32_32x32x64_f8f6f4(
          ua.v, b0[q], acc0, 0, 0, 0, 0x7F7F7F7F, 0, 0x7F7F7F7F);
      acc1 = __builtin_amdgcn_mfma_scale_f32_32x32x64_f8f6f4(
          ua.v, b1[q], acc1, 0, 0, 0, 0x7F7F7F7F, 0, 0x7F7F7F7F);
    }
    lse_update(acc0, m0, l0);
    lse_update(acc1, m1, l1);
  }

  // lanes l and l+32 hold the same i with complementary j-subsets: one swap
#pragma unroll
  for (int p = 0; p < 2; ++p) {
    float m = p ? m1 : m0;
    float l = p ? l1 : l0;
    const float mo = __shfl_xor(m, 32);
    const float lo = __shfl_xor(l, 32);
    const float mn = fmaxf(m, mo);
    l = l * __builtin_amdgcn_exp2f(m - mn) + lo * __builtin_amdgcn_exp2f(mo - mn);
    if (h == 0) {
      const int i = iBase + p * 32 + r32;
      // log2-domain partial lse; [chunk][i] layout: lane-coalesced store
      plse[(size_t)chunk * BATCH + i] = mn + __builtin_amdgcn_logf(l);
    }
  }
}

// ---------- pass 3: per-row combine + grid reduction (last-block ticket) ---
__global__ __launch_bounds__(256) void finalize_kernel(
    const float* __restrict__ plse, const float* __restrict__ pos,
    float2* __restrict__ bpart, unsigned int* __restrict__ counter,
    float* __restrict__ out) {
  const int tid = threadIdx.x;
  const int row = blockIdx.x * 256 + tid;
  float v[64];
#pragma unroll
  for (int c = 0; c < 64; ++c) v[c] = plse[(size_t)c * BATCH + row];
  float M = v[0];
#pragma unroll
  for (int c = 1; c < 64; ++c) M = fmaxf(M, v[c]);
  float S = 0.0f;
#pragma unroll
  for (int c = 0; c < 64; ++c) S += __builtin_amdgcn_exp2f(v[c] - M);
  const float lse = LN2F * (M + __builtin_amdgcn_logf(S));  // natural-log lse
  const float pv  = pos[row];
  float lsum = lse - 1000.0f * pv;
  float psum = pv;
#pragma unroll
  for (int msk = 1; msk < 64; msk <<= 1) {
    lsum += __shfl_xor(lsum, msk);
    psum += __shfl_xor(psum, msk);
  }
  __shared__ float sl[4], sp[4];
  const int w = tid >> 6, lane = tid & 63;
  if (lane == 0) { sl[w] = lsum; sp[w] = psum; }
  __syncthreads();
  if (tid == 0) {
    union { float2 f; unsigned long long u; } pk;
    pk.f = make_float2(sl[0] + sl[1] + sl[2] + sl[3],
                       sp[0] + sp[1] + sp[2] + sp[3]);
    __hip_atomic_store((unsigned long long*)&bpart[blockIdx.x], pk.u,
                       __ATOMIC_RELEASE, __HIP_MEMORY_SCOPE_AGENT);
    const unsigned int t = __hip_atomic_fetch_add(
        counter, 1u, __ATOMIC_ACQ_REL, __HIP_MEMORY_SCOPE_AGENT);
    if (t == 31u) {  // last block: deterministic ordered reduce of 32 partials
      float L = 0.f, P = 0.f;
#pragma unroll
      for (int i = 0; i < 32; ++i) {
        union { float2 f; unsigned long long u; } q2;
        q2.u = __hip_atomic_load((const unsigned long long*)&bpart[i],
                                 __ATOMIC_ACQUIRE, __HIP_MEMORY_SCOPE_AGENT);
        L += q2.f.x; P += q2.f.y;
      }
      out[0] = L / (float)BATCH;  // loss
      out[1] = P;                 // sum(positives)
    }
  }
}

extern "C" void kernel_launch(void* const* d_in, const int* in_sizes, int n_in,
                              void* d_out, int out_size, void* d_ws, size_t ws_size,
                              hipStream_t stream) {
  const float* p1 = (const float*)d_in[0];
  const float* p2 = (const float*)d_in[1];
  float* out = (float*)d_out;
  uint8_t* ws = (uint8_t*)d_ws;

  uint8_t* Zi8          = ws;                                                  // 2 MB (tiled)
  uint8_t* Zj8          = ws + (size_t)2 * 1024 * 1024;                        // 2 MB (tiled)
  float* pos            = (float*)(ws + (size_t)4 * 1024 * 1024);              // 32 KB
  float2* bpart         = (float2*)(ws + (size_t)4 * 1024 * 1024 + 32 * 1024); // 256 B
  unsigned int* counter = (unsigned int*)(ws + (size_t)4 * 1024 * 1024 + 40 * 1024); // 4 B
  float* plse           = (float*)(ws + (size_t)4 * 1024 * 1024 + 64 * 1024);  // 2 MB

  hipMemsetAsync(counter, 0, sizeof(unsigned int), stream);
  prep_kernel<<<dim3(2048), dim3(256), 0, stream>>>(p1, p2, Zi8, Zj8, pos);
  lse_kernel<<<dim3(2048), dim3(256), 0, stream>>>(Zi8, Zj8, plse);
  finalize_kernel<<<dim3(32), dim3(256), 0, stream>>>(plse, pos, bpart, counter, out);
}

// Round 11
// 44.306 us; speedup vs baseline: 1.9532x; 1.0408x over previous
//
#include <hip/hip_runtime.h>
#include <hip/hip_fp8.h>
#include <stdint.h>
#include <stddef.h>

#define BATCH 8192
#define DIM   256

#define LN2F 0.6931471805599453f
// operand quantization scales; product = 1000*log2(e) = 1442.6950408889634
// so MFMA accs are directly exp2-domain scores (no dequant in hot loop).
#define SCALE_ZJ 16.0f                 // A side (staged)
#define SCALE_ZI 90.16844005556021f    // B side (regs)

typedef int   v4i    __attribute__((ext_vector_type(4)));   // 16B (4 VGPR)
typedef int   v8i    __attribute__((ext_vector_type(8)));   // 32B fp8 frag (8 VGPR)
typedef float f32x16 __attribute__((ext_vector_type(16)));  // 32x32 MFMA acc

// Fragment-slot-tiled layout for Zi8/Zj8 (tile = 32 rows x 256B = 8KB):
//   elem(row, kb) -> tile(row>>5)*8192 + q*2048 + c*1024 + (32h + (row&31))*16 + b
//   where kb = q*64 + h*32 + c*16 + b  (q<4, h<2, c<2, b<16).
// Slot index (32h + r32) == MFMA lane id, so:
//   - A-frag ds_read: one vaddr (lane*16) + imm offsets, conflict-free (R7: 0)
//   - staging: identity mapping, linear & fully coalesced
//   - B-frag global loads: lane*16 contiguous, fully coalesced.
// R10 post-mortem: fragments are now built as two v4i loads concatenated with
// __builtin_shufflevector (register-only) — the previous union{int4[2];v8i}
// type-pun risks failed SROA -> scratch round-trip on the MFMA critical path
// (rule #20), which would explain the persistent ~4x gap to the pipe floor.

// ---------- helpers ----------
static __device__ __forceinline__ uint8_t f2fp8(float f) {
  __hip_fp8_e4m3 q(f);                       // OCP e4m3fn, RNE+sat
  return *reinterpret_cast<uint8_t*>(&q);
}

static __device__ __forceinline__ v8i cat8(v4i lo, v4i hi) {
  return __builtin_shufflevector(lo, hi, 0, 1, 2, 3, 4, 5, 6, 7);
}

// stage one 8KB tile: identity mapping (LDS offset == source offset)
static __device__ __forceinline__ void stage8(const uint8_t* __restrict__ src,
                                              uint8_t* dst, int tid) {
#pragma unroll
  for (int it = 0; it < 2; ++it) {
    const int off = it * 4096 + tid * 16;
    __builtin_amdgcn_global_load_lds(
        (const __attribute__((address_space(1))) void*)(src + off),
        (__attribute__((address_space(3))) void*)(dst + off), 16, 0, 0);
  }
}

// ---------- pass 1: normalize, exact fp32 positives, tiled fp8 store -------
__global__ __launch_bounds__(256) void prep_kernel(
    const float* __restrict__ p1, const float* __restrict__ p2,
    uint8_t* __restrict__ Zi8, uint8_t* __restrict__ Zj8,
    float* __restrict__ pos) {
  const int lane = threadIdx.x & 63;
  const int w    = threadIdx.x >> 6;
  const int row  = blockIdx.x * 4 + w;   // one wave per row

  const float4 x1 = ((const float4*)p1)[row * 64 + lane];
  const float4 x2 = ((const float4*)p2)[row * 64 + lane];
  float ss1 = x1.x * x1.x + x1.y * x1.y + x1.z * x1.z + x1.w * x1.w;
  float ss2 = x2.x * x2.x + x2.y * x2.y + x2.z * x2.z + x2.w * x2.w;
  float d   = x1.x * x2.x + x1.y * x2.y + x1.z * x2.z + x1.w * x2.w;
#pragma unroll
  for (int m = 1; m < 64; m <<= 1) {
    ss1 += __shfl_xor(ss1, m);
    ss2 += __shfl_xor(ss2, m);
    d   += __shfl_xor(d, m);
  }
  const float n1 = fmaxf(sqrtf(ss1), 1e-12f);
  const float n2 = fmaxf(sqrtf(ss2), 1e-12f);
  if (lane == 0) pos[row] = d / (n1 * n2);          // exact fp32 diagonal

  const float sI = SCALE_ZI / n1;
  const float sJ = SCALE_ZJ / n2;
  uchar4 u1, u2;
  u1.x = f2fp8(x1.x * sI); u1.y = f2fp8(x1.y * sI);
  u1.z = f2fp8(x1.z * sI); u1.w = f2fp8(x1.w * sI);
  u2.x = f2fp8(x2.x * sJ); u2.y = f2fp8(x2.y * sJ);
  u2.z = f2fp8(x2.z * sJ); u2.w = f2fp8(x2.w * sJ);

  // lane holds kb = 4*lane .. 4*lane+3 -> tiled address
  const size_t tb = (size_t)(row >> 5) * 8192;
  const int off = (lane >> 4) * 2048 + ((lane >> 2) & 1) * 1024 +
                  (((lane >> 3) & 1) * 32 + (row & 31)) * 16 + (lane & 3) * 4;
  *(uchar4*)(Zi8 + tb + off) = u1;
  *(uchar4*)(Zj8 + tb + off) = u2;
}

// ---------- online lse update for one 16-score acc block (lean temps) ------
static __device__ __forceinline__ void lse_update(const f32x16& acc,
                                                  float& m, float& l) {
  float t0 = fmaxf(fmaxf(acc[0],  acc[1]),  acc[2]);
  float t1 = fmaxf(fmaxf(acc[3],  acc[4]),  acc[5]);
  float t2 = fmaxf(fmaxf(acc[6],  acc[7]),  acc[8]);
  float t3 = fmaxf(fmaxf(acc[9],  acc[10]), acc[11]);
  t0 = fmaxf(fmaxf(t0, t1), fmaxf(fmaxf(acc[12], acc[13]), acc[14]));
  t2 = fmaxf(fmaxf(t2, t3), acc[15]);
  const float mn = fmaxf(m, fmaxf(t0, t2));
  float s0 = 0.f, s1 = 0.f;
#pragma unroll
  for (int r = 0; r < 16; r += 2) {
    s0 += __builtin_amdgcn_exp2f(acc[r + 0] - mn);
    s1 += __builtin_amdgcn_exp2f(acc[r + 1] - mn);
  }
  l = l * __builtin_amdgcn_exp2f(m - mn) + (s0 + s1);
  m = mn;
}

// ---------- pass 2: fused fp8 MFMA GEMM + online logsumexp ----------
// acc = mfma_scale_32x32x64(A=Zj_frag, B=Zi_frag, unit scales) -> D[j][i],
// col(lane&31)=i. Each lane owns TWO i rows; scalar (m,l) per row.
// grid = 32 row-blocks (256 i) x 32 j-chunks (256 cols); chunk = bid&31 so
// same-chunk blocks share an XCD (bid%8 == chunk%8), Zj slice L2-local.
// R6 schedule (best measured): 4x8KB LDS ring, 2 tiles per barrier phase,
// prefetch issued right after the barrier, setprio on MFMA cluster, (256,3)
// (the only proven spill-free cap: R5/R7 showed min-waves=4 clamps to 64
// VGPR and spills accs to scratch).
__global__ __launch_bounds__(256, 3) void lse_kernel(
    const uint8_t* __restrict__ Zi8, const uint8_t* __restrict__ Zj8,
    float* __restrict__ plse) {
  const int bid   = blockIdx.x;
  const int chunk = bid & 31;
  const int rb    = bid >> 5;
  const int tid   = threadIdx.x;
  const int lane  = tid & 63;
  const int r32   = lane & 31;
  const int h     = lane >> 5;
  const int w     = tid >> 6;
  const int iBase = rb * 256 + w * 64;

  __shared__ __align__(16) uint8_t lds[4][8192];

  const uint8_t* src = Zj8 + (size_t)chunk * 65536;   // 8 tiles = 256 cols
  stage8(src, &lds[0][0], tid);
  stage8(src + 8192, &lds[1][0], tid);

  // B fragments: this wave's two i-tiles, all of K=256, coalesced tiled loads,
  // register-only concat (no union).
  v8i b0[4], b1[4];
  const uint8_t* zb = Zi8 + (size_t)(rb * 8 + w * 2) * 8192 + lane * 16;
#pragma unroll
  for (int q = 0; q < 4; ++q) {
    b0[q] = cat8(*(const v4i*)(zb + q * 2048),
                 *(const v4i*)(zb + q * 2048 + 1024));
    b1[q] = cat8(*(const v4i*)(zb + 8192 + q * 2048),
                 *(const v4i*)(zb + 8192 + q * 2048 + 1024));
  }
#pragma unroll
  for (int q = 0; q < 4; ++q) { asm("" : "+v"(b0[q])); asm("" : "+v"(b1[q])); }

  float m0 = -1e30f, l0 = 0.f, m1 = -1e30f, l1 = 0.f;

  for (int s = 0; s < 4; ++s) {
    __syncthreads();  // tiles 2s,2s+1 resident; reused bufs fully consumed
    if (s < 3) {
      stage8(src + (size_t)(2 * s + 2) * 8192, &lds[(2 * s + 2) & 3][0], tid);
      stage8(src + (size_t)(2 * s + 3) * 8192, &lds[(2 * s + 3) & 3][0], tid);
    }
#pragma unroll
    for (int sub = 0; sub < 2; ++sub) {
      const uint8_t* buf = &lds[(2 * s + sub) & 3][0] + lane * 16;
      f32x16 acc0 = {}, acc1 = {};
      __builtin_amdgcn_s_setprio(1);
#pragma unroll
      for (int q = 0; q < 4; ++q) {
        const v8i av = cat8(*(const v4i*)(buf + q * 2048),        // imm-offset,
                            *(const v4i*)(buf + q * 2048 + 1024)); // conflict-free
        acc0 = __builtin_amdgcn_mfma_scale_f32_32x32x64_f8f6f4(
            av, b0[q], acc0, 0, 0, 0, 0x7F7F7F7F, 0, 0x7F7F7F7F);
        acc1 = __builtin_amdgcn_mfma_scale_f32_32x32x64_f8f6f4(
            av, b1[q], acc1, 0, 0, 0, 0x7F7F7F7F, 0, 0x7F7F7F7F);
      }
      __builtin_amdgcn_s_setprio(0);
      lse_update(acc0, m0, l0);
      lse_update(acc1, m1, l1);
    }
  }

  // lanes l and l+32 hold the same i with complementary j-subsets: one swap
#pragma unroll
  for (int p = 0; p < 2; ++p) {
    float m = p ? m1 : m0;
    float l = p ? l1 : l0;
    const float mo = __shfl_xor(m, 32);
    const float lo = __shfl_xor(l, 32);
    const float mn = fmaxf(m, mo);
    l = l * __builtin_amdgcn_exp2f(m - mn) + lo * __builtin_amdgcn_exp2f(mo - mn);
    if (h == 0) {
      const int i = iBase + p * 32 + r32;
      // log2-domain partial lse; [chunk][i] layout: lane-coalesced store
      plse[(size_t)chunk * BATCH + i] = mn + __builtin_amdgcn_logf(l);
    }
  }
}

// ---------- pass 3: per-row combine + grid reduction (last-block ticket) ---
__global__ __launch_bounds__(256) void finalize_kernel(
    const float* __restrict__ plse, const float* __restrict__ pos,
    float2* __restrict__ bpart, unsigned int* __restrict__ counter,
    float* __restrict__ out) {
  const int tid = threadIdx.x;
  const int row = blockIdx.x * 256 + tid;
  float v[32];
#pragma unroll
  for (int c = 0; c < 32; ++c) v[c] = plse[(size_t)c * BATCH + row];
  float M = v[0];
#pragma unroll
  for (int c = 1; c < 32; ++c) M = fmaxf(M, v[c]);
  float S = 0.0f;
#pragma unroll
  for (int c = 0; c < 32; ++c) S += __builtin_amdgcn_exp2f(v[c] - M);
  const float lse = LN2F * (M + __builtin_amdgcn_logf(S));  // natural-log lse
  const float pv  = pos[row];
  float lsum = lse - 1000.0f * pv;
  float psum = pv;
#pragma unroll
  for (int msk = 1; msk < 64; msk <<= 1) {
    lsum += __shfl_xor(lsum, msk);
    psum += __shfl_xor(psum, msk);
  }
  __shared__ float sl[4], sp[4];
  const int w = tid >> 6, lane = tid & 63;
  if (lane == 0) { sl[w] = lsum; sp[w] = psum; }
  __syncthreads();
  if (tid == 0) {
    union { float2 f; unsigned long long u; } pk;
    pk.f = make_float2(sl[0] + sl[1] + sl[2] + sl[3],
                       sp[0] + sp[1] + sp[2] + sp[3]);
    __hip_atomic_store((unsigned long long*)&bpart[blockIdx.x], pk.u,
                       __ATOMIC_RELEASE, __HIP_MEMORY_SCOPE_AGENT);
    const unsigned int t = __hip_atomic_fetch_add(
        counter, 1u, __ATOMIC_ACQ_REL, __HIP_MEMORY_SCOPE_AGENT);
    if (t == 31u) {  // last block: deterministic ordered reduce of 32 partials
      float L = 0.f, P = 0.f;
#pragma unroll
      for (int i = 0; i < 32; ++i) {
        union { float2 f; unsigned long long u; } q2;
        q2.u = __hip_atomic_load((const unsigned long long*)&bpart[i],
                                 __ATOMIC_ACQUIRE, __HIP_MEMORY_SCOPE_AGENT);
        L += q2.f.x; P += q2.f.y;
      }
      out[0] = L / (float)BATCH;  // loss
      out[1] = P;                 // sum(positives)
    }
  }
}

extern "C" void kernel_launch(void* const* d_in, const int* in_sizes, int n_in,
                              void* d_out, int out_size, void* d_ws, size_t ws_size,
                              hipStream_t stream) {
  const float* p1 = (const float*)d_in[0];
  const float* p2 = (const float*)d_in[1];
  float* out = (float*)d_out;
  uint8_t* ws = (uint8_t*)d_ws;

  uint8_t* Zi8          = ws;                                                  // 2 MB (tiled)
  uint8_t* Zj8          = ws + (size_t)2 * 1024 * 1024;                        // 2 MB (tiled)
  float* pos            = (float*)(ws + (size_t)4 * 1024 * 1024);              // 32 KB
  float2* bpart         = (float2*)(ws + (size_t)4 * 1024 * 1024 + 32 * 1024); // 256 B
  unsigned int* counter = (unsigned int*)(ws + (size_t)4 * 1024 * 1024 + 40 * 1024); // 4 B
  float* plse           = (float*)(ws + (size_t)4 * 1024 * 1024 + 64 * 1024);  // 1 MB

  hipMemsetAsync(counter, 0, sizeof(unsigned int), stream);
  prep_kernel<<<dim3(2048), dim3(256), 0, stream>>>(p1, p2, Zi8, Zj8, pos);
  lse_kernel<<<dim3(1024), dim3(256), 0, stream>>>(Zi8, Zj8, plse);
  finalize_kernel<<<dim3(32), dim3(256), 0, stream>>>(plse, pos, bpart, counter, out);
}